// Round 18
// baseline (260.620 us; speedup 1.0000x reference)
//
#include <hip/hip_runtime.h>

#define ND 50000
#define NEDGE 640000
#define CH 128
#define MP 50048          // 391*128 padded rows
#define NREL4 (4 * ND)    // 200000
#define GB (MP / 128)     // 391 blocks per GEMM half
#define NBUCK 391         // buckets per relation (128 nodes each)
#define BCAP 2000         // padded bucket capacity (mean 1638, sigma 40)
#define CHUNK 4096        // edges per scatter block
#define EPT 16            // edges per thread in scatter

#define NCHUNKS ((NEDGE + CHUNK - 1) / CHUNK)   // 157
#define SCAT_BLOCKS (4 * NCHUNKS)               // 628
#define F2B_BLOCKS (2 * (ND * CH / 4) / 256)    // 12500
#define PACKW_BLOCKS ((12 * 16384) / 256)       // 768
#define PREP_BLOCKS (SCAT_BLOCKS + F2B_BLOCKS + PACKW_BLOCKS)

#define GGRID8 6256   // 8 * 782; per rel 1564 rb-slots * 32 nodes >= ND

using f32x4 = __attribute__((ext_vector_type(4))) float;
using bf16x8 = __attribute__((ext_vector_type(8))) __bf16;
using u32x4 = __attribute__((ext_vector_type(4))) unsigned int;
using u32x2 = __attribute__((ext_vector_type(2))) unsigned int;

static __device__ __forceinline__ unsigned short f2bf(float f) {
    unsigned int u = __float_as_uint(f);
    unsigned int r = (u + 0x7fffu + ((u >> 16) & 1u)) >> 16;
    return (unsigned short)r;
}

// v_cvt_pk_bf16_f32: packs RNE(lo), RNE(hi) into one u32 (gfx950; no builtin)
static __device__ __forceinline__ unsigned int cvt_pk_bf16(float lo, float hi) {
    unsigned int r;
    asm volatile("v_cvt_pk_bf16_f32 %0, %1, %2" : "=v"(r) : "v"(lo), "v"(hi));
    return r;
}

// async global->LDS, 16 B per lane; dest linear => wave-uniform-base + lane*16 holds
static __device__ __forceinline__ void gl_lds16(const unsigned short* g, unsigned short* l) {
    __builtin_amdgcn_global_load_lds(
        (const __attribute__((address_space(1))) unsigned int*)g,
        (__attribute__((address_space(3))) unsigned int*)l, 16, 0, 0);
}

// ---------------- fused prep: edge scatter  ||  fp32->bf16 convert  ||  W pack ----------------
struct PrepArgs {
    const int* s[4];            // src arrays per rel
    const int* d[4];            // dst arrays per rel
    int* cursor;                // [4*NBUCK], zeroed before launch
    unsigned int* pairbuf;
    const float* hd;
    const float* hp;
    unsigned short* hdb;
    unsigned short* hpb;
    const float* w[12];
    unsigned short* wf;
};

__global__ __launch_bounds__(256) void prep_kernel(PrepArgs pa) {
    __shared__ int lcnt[NBUCK];
    __shared__ int lbase[NBUCK];
    __shared__ int lcur[NBUCK];
    int bid = blockIdx.x;
    int tid = threadIdx.x;

    if (bid < SCAT_BLOCKS) {
        // ---- pass C: scatter edges into coarse buckets ----
        int rel = bid / NCHUNKS;
        int chunk = bid - rel * NCHUNKS;
        const int* S = pa.s[rel];
        const int* D = pa.d[rel];
        int e0 = chunk * CHUNK;
        int cnt_edges = NEDGE - e0;
        if (cnt_edges > CHUNK) cnt_edges = CHUNK;
        for (int i = tid; i < NBUCK; i += 256) { lcnt[i] = 0; lcur[i] = 0; }
        __syncthreads();
        unsigned int v[EPT];
        #pragma unroll
        for (int i = 0; i < EPT; ++i) {
            int o = i * 256 + tid;
            if (o < cnt_edges) {
                unsigned int sv = (unsigned int)S[e0 + o];
                unsigned int dv = (unsigned int)D[e0 + o];
                v[i] = sv | (dv << 16);
                atomicAdd(&lcnt[dv >> 7], 1);
            }
        }
        __syncthreads();
        for (int b = tid; b < NBUCK; b += 256) {
            int c = lcnt[b];
            if (c > 0) {
                int off = atomicAdd(&pa.cursor[rel * NBUCK + b], c);
                lbase[b] = (rel * NBUCK + b) * BCAP + off;
            }
        }
        __syncthreads();
        #pragma unroll
        for (int i = 0; i < EPT; ++i) {
            int o = i * 256 + tid;
            if (o < cnt_edges) {
                unsigned int vv = v[i];
                int b = vv >> 23;            // dst >> 7
                int idx = atomicAdd(&lcur[b], 1);
                int go = lbase[b] + idx - (rel * NBUCK + b) * BCAP;
                if (go < BCAP) pa.pairbuf[lbase[b] + idx] = vv;
            }
        }
    } else if (bid < SCAT_BLOCKS + F2B_BLOCKS) {
        // ---- fp32 -> bf16 bulk convert, both tables (non-temporal both sides) ----
        const int n4 = ND * CH / 4;
        int i = (bid - SCAT_BLOCKS) * 256 + tid;   // [0, 2*n4)
        const float* in = pa.hd;
        unsigned short* out = pa.hdb;
        int j = i;
        if (i >= n4) { in = pa.hp; out = pa.hpb; j = i - n4; }
        f32x4 v = __builtin_nontemporal_load(reinterpret_cast<const f32x4*>(in) + j);
        u32x2 o;
        o.x = cvt_pk_bf16(v.x, v.y);
        o.y = cvt_pk_bf16(v.z, v.w);
        __builtin_nontemporal_store(o, reinterpret_cast<u32x2*>(out) + j);
    } else {
        // ---- W pack: fp32 [k][n] -> bf16 MFMA B-fragment order ----
        // layer-2 mats (6..11): K-permuted to match the permuted od1 storage:
        // storage position p holds original channel c(p) = (p>>3) | ((p&7)<<4)
        int idx = (bid - SCAT_BLOCKS - F2B_BLOCKS) * 256 + tid;   // [0, 12*16384)
        int mat = idx >> 14;
        const float* W = pa.w[mat];
        int r = idx & 16383;
        int j = r & 7;
        int l = (r >> 3) & 63;
        int s = (r >> 9) & 3;
        int nt = (r >> 11) & 7;
        int k = s * 32 + ((l >> 4) << 3) + j;
        if (mat >= 6) k = (k >> 3) | ((k & 7) << 4);
        int n = nt * 16 + (l & 15);
        pa.wf[idx] = f2bf(W[k * CH + n]);
    }
}

// ---------------- pass B' — scan 1564 bucket counts -> global CSR bases ----------------
__global__ __launch_bounds__(1024) void scan_buckets(const int* __restrict__ cnt,
                                                     int* __restrict__ base,
                                                     int* __restrict__ total_out) {
    __shared__ int buf[1024];
    __shared__ int carry_s;
    int tid = threadIdx.x;
    if (tid == 0) carry_s = 0;
    __syncthreads();
    for (int c0 = 0; c0 < 4 * NBUCK; c0 += 1024) {
        int i = c0 + tid;
        int val = (i < 4 * NBUCK) ? cnt[i] : 0;
        buf[tid] = val;
        __syncthreads();
        for (int off = 1; off < 1024; off <<= 1) {
            int t = (tid >= off) ? buf[tid - off] : 0;
            __syncthreads();
            buf[tid] += t;
            __syncthreads();
        }
        int carry = carry_s;
        if (i < 4 * NBUCK) base[i] = carry + buf[tid] - val;
        __syncthreads();
        if (tid == 1023) carry_s = carry + buf[1023];
        __syncthreads();
    }
    if (tid == 0) *total_out = carry_s;
}

// ---------------- pass D — finalize bucket: rowptr + compact ushort col ----------------
__global__ __launch_bounds__(256) void bucket_finalize(
    const unsigned int* __restrict__ pairbuf, const int* __restrict__ cursor,
    const int* __restrict__ base_arr, int* __restrict__ rowptr,
    unsigned short* __restrict__ col16) {
    int b = blockIdx.x;                  // 0..4*NBUCK-1
    int rel = b / NBUCK;
    int bb = b - rel * NBUCK;
    int cnt = cursor[b];
    if (cnt > BCAP) cnt = BCAP;
    int base = base_arr[b];
    const unsigned int* items = pairbuf + (size_t)b * BCAP;
    __shared__ int lcnt[128];
    __shared__ int lpfx[128];
    __shared__ int lcur[128];
    int tid = threadIdx.x;
    if (tid < 128) { lcnt[tid] = 0; lcur[tid] = 0; }
    __syncthreads();
    for (int i = tid; i < cnt; i += 256) atomicAdd(&lcnt[(items[i] >> 16) & 127], 1);
    __syncthreads();
    if (tid < 128) lpfx[tid] = lcnt[tid];
    __syncthreads();
    for (int off = 1; off < 128; off <<= 1) {
        int t = (tid < 128 && tid >= off) ? lpfx[tid - off] : 0;
        __syncthreads();
        if (tid < 128) lpfx[tid] += t;
        __syncthreads();
    }
    int node0 = bb * 128;
    if (tid < 128 && node0 + tid < ND)
        rowptr[rel * ND + node0 + tid] = base + lpfx[tid] - lcnt[tid];
    __syncthreads();
    for (int i = tid; i < cnt; i += 256) {
        unsigned int vv = items[i];
        int nl = (vv >> 16) & 127;
        int idx = atomicAdd(&lcur[nl], 1);
        col16[base + (lpfx[nl] - lcnt[nl]) + idx] = (unsigned short)(vv & 0xffffu);
    }
}

// ---------------- fused 4-relation segment gather-sum, channel-split 2-pass ----------------
// 8 nodes per wave (sub = 8 lanes x 16 B), depth-8 edge pipeline, NT output stores.
struct GatherArgs {
    const unsigned short* h[4];
    unsigned short* out[4];
    const int* rowptr;          // concatenated, rel r node v -> rowptr[r*ND+v]
    const unsigned short* col;  // concatenated u16 src slots
};

static __device__ __forceinline__ void addq(uint4 q, float2* acc) {
    acc[0] += make_float2(__uint_as_float(q.x << 16), __uint_as_float(q.x & 0xffff0000u));
    acc[1] += make_float2(__uint_as_float(q.y << 16), __uint_as_float(q.y & 0xffff0000u));
    acc[2] += make_float2(__uint_as_float(q.z << 16), __uint_as_float(q.z & 0xffff0000u));
    acc[3] += make_float2(__uint_as_float(q.w << 16), __uint_as_float(q.w & 0xffff0000u));
}

__global__ __launch_bounds__(256) void seg_gather8(GatherArgs ga, int pass) {
    int bid = blockIdx.x;                     // grid = GGRID8
    int rel = (bid & 7) >> 1;                 // XCD pair per relation
    int rb = ((bid >> 3) << 1) | (bid & 1);   // within-rel block index, [0,1564)
    int wib = threadIdx.x >> 6;
    int lane = threadIdx.x & 63;
    int sub = lane >> 3;                      // node slot within wave (8 nodes)
    int cl = (lane & 7) + pass * 8;           // 16 B slot within the half-row
    int v = rb * 32 + wib * 8 + sub;          // node id (may exceed ND)

    const uint4* h32 = reinterpret_cast<const uint4*>(ga.h[rel]);
    const int* rp = ga.rowptr + rel * ND;
    int s0 = 0, s1 = 0;
    if (v < ND) { s0 = rp[v]; s1 = rp[v + 1]; }
    const unsigned short* col = ga.col;

    float2 acc[4];
    acc[0] = acc[1] = acc[2] = acc[3] = make_float2(0.f, 0.f);

    int e = s0;
    for (; e + 8 <= s1; e += 8) {             // 8 independent edges in flight
        int si[8];
        #pragma unroll
        for (int j = 0; j < 8; ++j) si[j] = col[e + j];
        uint4 q[8];
        #pragma unroll
        for (int j = 0; j < 8; ++j) q[j] = h32[si[j] * 16 + cl];
        #pragma unroll
        for (int j = 0; j < 8; ++j) addq(q[j], acc);
    }
    if (e + 4 <= s1) {
        int s0_ = col[e], s1_ = col[e + 1], s2_ = col[e + 2], s3_ = col[e + 3];
        uint4 q0 = h32[s0_ * 16 + cl];
        uint4 q1 = h32[s1_ * 16 + cl];
        uint4 q2 = h32[s2_ * 16 + cl];
        uint4 q3 = h32[s3_ * 16 + cl];
        addq(q0, acc); addq(q1, acc); addq(q2, acc); addq(q3, acc);
        e += 4;
    }
    if (e + 2 <= s1) {
        int s0_ = col[e], s1_ = col[e + 1];
        uint4 q0 = h32[s0_ * 16 + cl];
        uint4 q1 = h32[s1_ * 16 + cl];
        addq(q0, acc); addq(q1, acc);
        e += 2;
    }
    if (e < s1) {
        uint4 q0 = h32[col[e] * 16 + cl];
        addq(q0, acc);
    }

    if (v < ND) {
        u32x4 o;
        o.x = cvt_pk_bf16(acc[0].x, acc[0].y);
        o.y = cvt_pk_bf16(acc[1].x, acc[1].y);
        o.z = cvt_pk_bf16(acc[2].x, acc[2].y);
        o.w = cvt_pk_bf16(acc[3].x, acc[3].y);
        __builtin_nontemporal_store(
            o, reinterpret_cast<u32x4*>(ga.out[rel]) + ((size_t)v * 16 + cl));
    }
}

// ---------------- fused MFMA GEMM, drug+protein halves ----------------
// 512 threads = 8 waves, 16 rows/wave, single 32 KB LDS W buffer, A prefetch 1 mat ahead.
// Epilogue stores are NON-TEMPORAL (outputs have no intra-dispatch reuse; keeps
// the A-panel stream resident in L2). Residual R also NT-loaded.
struct GemmArgs {
    const unsigned short* A[6];
    const unsigned short* W[6];
    const float* R[2];
    float* outf[2];
    unsigned short* outb[2];
    int M;
};

#define STAGE_W(Wm)                                                             \
    _Pragma("unroll")                                                           \
    for (int j = 0; j < 4; ++j)                                                 \
        gl_lds16((Wm) + (j * 512 + tid) * 8, &Wlds[(j * 512 + tid) * 8]);

#define COMPUTE_MAT()                                                           \
    _Pragma("unroll")                                                           \
    for (int s = 0; s < 4; ++s) {                                               \
        _Pragma("unroll")                                                       \
        for (int nt = 0; nt < 8; ++nt) {                                        \
            bf16x8 bb = *reinterpret_cast<const bf16x8*>(                       \
                &Wlds[((nt * 4 + s) * 64 + l) * 8]);                            \
            acc[nt] = __builtin_amdgcn_mfma_f32_16x16x32_bf16(                  \
                acur[s], bb, acc[nt], 0, 0, 0);                                 \
        }                                                                       \
    }

__global__ __launch_bounds__(512, 6) void mfma_gemm2(GemmArgs ga) {
    __shared__ unsigned short Wlds[16384];   // 32 KB: one packed W matrix

    int bid = blockIdx.x;
    int half = (bid >= GB) ? 1 : 0;
    int b = bid - half * GB;
    const float* R = ga.R[half];
    float* outf = ga.outf[half];
    unsigned short* outb = ga.outb[half];
    int M = ga.M;

    int tid = threadIdx.x;
    int w = tid >> 6;            // wave 0..7
    int l = tid & 63;
    int lrow = l & 15;
    int lk = l >> 4;
    int m0 = b * 128 + w * 16;   // 16 rows per wave

    size_t rowoff = (size_t)(m0 + lrow) * CH + lk * 8;

    const unsigned short* A0 = ga.A[half * 3 + 0];
    const unsigned short* A1 = ga.A[half * 3 + 1];
    const unsigned short* A2 = ga.A[half * 3 + 2];

    bf16x8 acur[4], anx[4];
    #pragma unroll
    for (int s = 0; s < 4; ++s)
        acur[s] = *reinterpret_cast<const bf16x8*>(A0 + rowoff + s * 32);
    STAGE_W(ga.W[half * 3 + 0]);

    f32x4 acc[8];
    #pragma unroll
    for (int nt = 0; nt < 8; ++nt) acc[nt] = (f32x4){0.f, 0.f, 0.f, 0.f};

    __syncthreads();                               // W0 staged, acur ready
    #pragma unroll
    for (int s = 0; s < 4; ++s)                    // prefetch A1 (overlaps MFMA)
        anx[s] = *reinterpret_cast<const bf16x8*>(A1 + rowoff + s * 32);
    COMPUTE_MAT();
    __syncthreads();                               // LDS free
    STAGE_W(ga.W[half * 3 + 1]);
    #pragma unroll
    for (int s = 0; s < 4; ++s) acur[s] = anx[s];
    __syncthreads();                               // W1 staged
    #pragma unroll
    for (int s = 0; s < 4; ++s)                    // prefetch A2
        anx[s] = *reinterpret_cast<const bf16x8*>(A2 + rowoff + s * 32);
    COMPUTE_MAT();
    __syncthreads();                               // LDS free
    STAGE_W(ga.W[half * 3 + 2]);
    #pragma unroll
    for (int s = 0; s < 4; ++s) acur[s] = anx[s];
    __syncthreads();                               // W2 staged
    COMPUTE_MAT();

    if (outf) {
        // layer 2: LDS transpose (2 chunks of 64 rows) -> coalesced residual+store
        float* lf = reinterpret_cast<float*>(Wlds);    // 32 KB = 64 rows x 128 fp32
        #pragma unroll
        for (int c = 0; c < 2; ++c) {
            __syncthreads();                           // LDS free for this chunk
            if ((w >> 2) == c) {
                int lr = (w & 3) * 16 + lk * 4;
                #pragma unroll
                for (int r = 0; r < 4; ++r)
                    #pragma unroll
                    for (int nt = 0; nt < 8; ++nt)
                        lf[(lr + r) * 128 + nt * 16 + lrow] = acc[nt][r];
            }
            __syncthreads();
            int rowbase = b * 128 + c * 64;
            #pragma unroll
            for (int k = 0; k < 4; ++k) {
                int f4 = k * 512 + tid;                // 64 rows x 32 float4
                int lr = f4 >> 5;
                int fc = f4 & 31;
                int row = rowbase + lr;
                if (row < M) {
                    f32x4 v = reinterpret_cast<f32x4*>(lf)[f4];
                    f32x4 rv = __builtin_nontemporal_load(
                        reinterpret_cast<const f32x4*>(R + (size_t)row * CH + fc * 4));
                    v.x = fmaxf(v.x + rv.x, 0.f);
                    v.y = fmaxf(v.y + rv.y, 0.f);
                    v.z = fmaxf(v.z + rv.z, 0.f);
                    v.w = fmaxf(v.w + rv.w, 0.f);
                    __builtin_nontemporal_store(
                        v, reinterpret_cast<f32x4*>(outf + (size_t)row * CH + fc * 4));
                }
            }
        }
    } else {
        // layer 1: K-permuted bf16, one NT uint4 store per r
        #pragma unroll
        for (int r = 0; r < 4; ++r) {
            int row = m0 + lk * 4 + r;
            if (row < M) {
                u32x4 o;
                o.x = cvt_pk_bf16(fmaxf(acc[0][r], 0.f), fmaxf(acc[1][r], 0.f));
                o.y = cvt_pk_bf16(fmaxf(acc[2][r], 0.f), fmaxf(acc[3][r], 0.f));
                o.z = cvt_pk_bf16(fmaxf(acc[4][r], 0.f), fmaxf(acc[5][r], 0.f));
                o.w = cvt_pk_bf16(fmaxf(acc[6][r], 0.f), fmaxf(acc[7][r], 0.f));
                __builtin_nontemporal_store(
                    o, reinterpret_cast<u32x4*>(outb + (size_t)row * CH + lrow * 8));
            }
        }
    }
}

// ---------------- launch ----------------

extern "C" void kernel_launch(void* const* d_in, const int* in_sizes, int n_in,
                              void* d_out, int out_size, void* d_ws, size_t ws_size,
                              hipStream_t stream) {
    const float* hd = (const float*)d_in[0];
    const float* hp = (const float*)d_in[1];

    float* outd = (float*)d_out;
    float* outp = outd + (size_t)ND * CH;

    char* ws = (char*)d_ws;
    size_t off = 0;
    auto alloc = [&](size_t bytes) -> char* {
        char* p = ws + off;
        off += (bytes + 255) & ~(size_t)255;
        return p;
    };
    int* rowptr = (int*)alloc((size_t)(NREL4 + 1) * 4);
    int* cursor = (int*)alloc((size_t)4 * NBUCK * 4);
    int* bbase = (int*)alloc((size_t)4 * NBUCK * 4);
    unsigned int* pairbuf = (unsigned int*)alloc((size_t)4 * NBUCK * BCAP * 4);
    unsigned short* col16 = (unsigned short*)alloc((size_t)4 * NEDGE * 2);
    unsigned short* hdb = (unsigned short*)alloc((size_t)MP * CH * 2);
    unsigned short* hpb = (unsigned short*)alloc((size_t)MP * CH * 2);
    unsigned short* od1d = (unsigned short*)alloc((size_t)MP * CH * 2);
    unsigned short* od1p = (unsigned short*)alloc((size_t)MP * CH * 2);
    unsigned short* agg[4];
    for (int r = 0; r < 4; ++r) agg[r] = (unsigned short*)alloc((size_t)MP * CH * 2);
    unsigned short* wfrag = (unsigned short*)alloc((size_t)12 * 16384 * 2);
    if (ws_size < off) return;  // workspace too small -> fail loudly

    const unsigned short* wf[12];
    for (int i = 0; i < 12; ++i) wf[i] = wfrag + (size_t)i * 16384;

    // ---- fused prep: scatter || f2b2 || pack_w  (rel order {dd, dp, pd, pp}) ----
    hipMemsetAsync(cursor, 0, (size_t)4 * NBUCK * 4, stream);
    PrepArgs pa;
    pa.s[0] = (const int*)d_in[2]; pa.s[1] = (const int*)d_in[3];
    pa.s[2] = (const int*)d_in[4]; pa.s[3] = (const int*)d_in[5];
    for (int r = 0; r < 4; ++r) pa.d[r] = pa.s[r] + NEDGE;
    pa.cursor = cursor; pa.pairbuf = pairbuf;
    pa.hd = hd; pa.hp = hp; pa.hdb = hdb; pa.hpb = hpb;
    for (int i = 0; i < 12; ++i) pa.w[i] = (const float*)d_in[6 + i];
    pa.wf = wfrag;
    prep_kernel<<<PREP_BLOCKS, 256, 0, stream>>>(pa);
    scan_buckets<<<1, 1024, 0, stream>>>(cursor, bbase, rowptr + NREL4);
    bucket_finalize<<<4 * NBUCK, 256, 0, stream>>>(pairbuf, cursor, bbase, rowptr, col16);

    // ---- layer 1 ----
    GatherArgs g1;
    g1.h[0] = hdb; g1.out[0] = agg[0];   // dd -> agg_dd
    g1.h[1] = hdb; g1.out[1] = agg[3];   // dp -> agg_dp
    g1.h[2] = hpb; g1.out[2] = agg[1];   // pd -> agg_pd
    g1.h[3] = hpb; g1.out[3] = agg[2];   // pp -> agg_pp
    g1.rowptr = rowptr; g1.col = col16;
    seg_gather8<<<GGRID8, 256, 0, stream>>>(g1, 0);
    seg_gather8<<<GGRID8, 256, 0, stream>>>(g1, 1);

    GemmArgs m1;
    m1.A[0] = hdb;  m1.A[1] = agg[0]; m1.A[2] = agg[1];
    m1.W[0] = wf[0]; m1.W[1] = wf[2]; m1.W[2] = wf[4];   // w1_sd, w1_dd, w1_pd
    m1.A[3] = hpb;  m1.A[4] = agg[2]; m1.A[5] = agg[3];
    m1.W[3] = wf[1]; m1.W[4] = wf[5]; m1.W[5] = wf[3];   // w1_sp, w1_pp, w1_dp
    m1.R[0] = nullptr; m1.R[1] = nullptr;
    m1.outf[0] = nullptr; m1.outf[1] = nullptr;
    m1.outb[0] = od1d; m1.outb[1] = od1p;
    m1.M = ND;
    mfma_gemm2<<<2 * GB, 512, 0, stream>>>(m1);

    // ---- layer 2 (od1 & its aggs live in K-permuted space; wf[6..11] match) ----
    GatherArgs g2 = g1;
    g2.h[0] = od1d; g2.h[1] = od1d; g2.h[2] = od1p; g2.h[3] = od1p;
    seg_gather8<<<GGRID8, 256, 0, stream>>>(g2, 0);
    seg_gather8<<<GGRID8, 256, 0, stream>>>(g2, 1);

    GemmArgs m2;
    m2.A[0] = od1d; m2.A[1] = agg[0]; m2.A[2] = agg[1];
    m2.W[0] = wf[6]; m2.W[1] = wf[8]; m2.W[2] = wf[10];  // w2_sd, w2_dd, w2_pd
    m2.A[3] = od1p; m2.A[4] = agg[2]; m2.A[5] = agg[3];
    m2.W[3] = wf[7]; m2.W[4] = wf[11]; m2.W[5] = wf[9];  // w2_sp, w2_pp, w2_dp
    m2.R[0] = hd; m2.R[1] = hp;
    m2.outf[0] = outd; m2.outf[1] = outp;
    m2.outb[0] = nullptr; m2.outb[1] = nullptr;
    m2.M = ND;
    mfma_gemm2<<<2 * GB, 512, 0, stream>>>(m2);
}

// Round 19
// 255.176 us; speedup vs baseline: 1.0213x; 1.0213x over previous
//
#include <hip/hip_runtime.h>

#define ND 50000
#define NEDGE 640000
#define CH 128
#define MP 50048          // 391*128 padded rows
#define NREL4 (4 * ND)    // 200000
#define GB (MP / 128)     // 391 blocks per GEMM half
#define NBUCK 391         // buckets per relation (128 nodes each)
#define BCAP 2000         // padded bucket capacity (mean 1638, sigma 40)
#define CHUNK 4096        // edges per scatter block
#define EPT 16            // edges per thread in scatter

#define NCHUNKS ((NEDGE + CHUNK - 1) / CHUNK)   // 157
#define SCAT_BLOCKS (4 * NCHUNKS)               // 628
#define F2B_BLOCKS (2 * (ND * CH / 4) / 256)    // 12500
#define PACKW_BLOCKS ((12 * 16384) / 256)       // 768
#define PREP_BLOCKS (SCAT_BLOCKS + F2B_BLOCKS + PACKW_BLOCKS)

#define GGRID8 6256   // 8 * 782; per rel 1564 rb-slots * 32 nodes >= ND

using f32x4 = __attribute__((ext_vector_type(4))) float;
using bf16x8 = __attribute__((ext_vector_type(8))) __bf16;
using u32x4 = __attribute__((ext_vector_type(4))) unsigned int;
using u32x2 = __attribute__((ext_vector_type(2))) unsigned int;

static __device__ __forceinline__ unsigned short f2bf(float f) {
    unsigned int u = __float_as_uint(f);
    unsigned int r = (u + 0x7fffu + ((u >> 16) & 1u)) >> 16;
    return (unsigned short)r;
}

// v_cvt_pk_bf16_f32: packs RNE(lo), RNE(hi) into one u32 (gfx950; no builtin)
static __device__ __forceinline__ unsigned int cvt_pk_bf16(float lo, float hi) {
    unsigned int r;
    asm volatile("v_cvt_pk_bf16_f32 %0, %1, %2" : "=v"(r) : "v"(lo), "v"(hi));
    return r;
}

// async global->LDS, 16 B per lane; dest linear => wave-uniform-base + lane*16 holds
static __device__ __forceinline__ void gl_lds16(const unsigned short* g, unsigned short* l) {
    __builtin_amdgcn_global_load_lds(
        (const __attribute__((address_space(1))) unsigned int*)g,
        (__attribute__((address_space(3))) unsigned int*)l, 16, 0, 0);
}

// ---------------- fused prep: edge scatter  ||  fp32->bf16 convert  ||  W pack ----------------
struct PrepArgs {
    const int* s[4];            // src arrays per rel
    const int* d[4];            // dst arrays per rel
    int* cursor;                // [4*NBUCK], zeroed before launch
    unsigned int* pairbuf;
    const float* hd;
    const float* hp;
    unsigned short* hdb;
    unsigned short* hpb;
    const float* w[12];
    unsigned short* wf;
};

__global__ __launch_bounds__(256) void prep_kernel(PrepArgs pa) {
    __shared__ int lcnt[NBUCK];
    __shared__ int lbase[NBUCK];
    __shared__ int lcur[NBUCK];
    int bid = blockIdx.x;
    int tid = threadIdx.x;

    if (bid < SCAT_BLOCKS) {
        // ---- pass C: scatter edges into coarse buckets ----
        int rel = bid / NCHUNKS;
        int chunk = bid - rel * NCHUNKS;
        const int* S = pa.s[rel];
        const int* D = pa.d[rel];
        int e0 = chunk * CHUNK;
        int cnt_edges = NEDGE - e0;
        if (cnt_edges > CHUNK) cnt_edges = CHUNK;
        for (int i = tid; i < NBUCK; i += 256) { lcnt[i] = 0; lcur[i] = 0; }
        __syncthreads();
        unsigned int v[EPT];
        #pragma unroll
        for (int i = 0; i < EPT; ++i) {
            int o = i * 256 + tid;
            if (o < cnt_edges) {
                unsigned int sv = (unsigned int)S[e0 + o];
                unsigned int dv = (unsigned int)D[e0 + o];
                v[i] = sv | (dv << 16);
                atomicAdd(&lcnt[dv >> 7], 1);
            }
        }
        __syncthreads();
        for (int b = tid; b < NBUCK; b += 256) {
            int c = lcnt[b];
            if (c > 0) {
                int off = atomicAdd(&pa.cursor[rel * NBUCK + b], c);
                lbase[b] = (rel * NBUCK + b) * BCAP + off;
            }
        }
        __syncthreads();
        #pragma unroll
        for (int i = 0; i < EPT; ++i) {
            int o = i * 256 + tid;
            if (o < cnt_edges) {
                unsigned int vv = v[i];
                int b = vv >> 23;            // dst >> 7
                int idx = atomicAdd(&lcur[b], 1);
                int go = lbase[b] + idx - (rel * NBUCK + b) * BCAP;
                if (go < BCAP) pa.pairbuf[lbase[b] + idx] = vv;
            }
        }
    } else if (bid < SCAT_BLOCKS + F2B_BLOCKS) {
        // ---- fp32 -> bf16 bulk convert, both tables (non-temporal both sides) ----
        const int n4 = ND * CH / 4;
        int i = (bid - SCAT_BLOCKS) * 256 + tid;   // [0, 2*n4)
        const float* in = pa.hd;
        unsigned short* out = pa.hdb;
        int j = i;
        if (i >= n4) { in = pa.hp; out = pa.hpb; j = i - n4; }
        f32x4 v = __builtin_nontemporal_load(reinterpret_cast<const f32x4*>(in) + j);
        u32x2 o;
        o.x = cvt_pk_bf16(v.x, v.y);
        o.y = cvt_pk_bf16(v.z, v.w);
        __builtin_nontemporal_store(o, reinterpret_cast<u32x2*>(out) + j);
    } else {
        // ---- W pack: fp32 [k][n] -> bf16 MFMA B-fragment order ----
        // layer-2 mats (6..11): K-permuted to match the permuted od1 storage:
        // storage position p holds original channel c(p) = (p>>3) | ((p&7)<<4)
        int idx = (bid - SCAT_BLOCKS - F2B_BLOCKS) * 256 + tid;   // [0, 12*16384)
        int mat = idx >> 14;
        const float* W = pa.w[mat];
        int r = idx & 16383;
        int j = r & 7;
        int l = (r >> 3) & 63;
        int s = (r >> 9) & 3;
        int nt = (r >> 11) & 7;
        int k = s * 32 + ((l >> 4) << 3) + j;
        if (mat >= 6) k = (k >> 3) | ((k & 7) << 4);
        int n = nt * 16 + (l & 15);
        pa.wf[idx] = f2bf(W[k * CH + n]);
    }
}

// ---------------- pass B' — scan 1564 bucket counts -> global CSR bases ----------------
__global__ __launch_bounds__(1024) void scan_buckets(const int* __restrict__ cnt,
                                                     int* __restrict__ base,
                                                     int* __restrict__ total_out) {
    __shared__ int buf[1024];
    __shared__ int carry_s;
    int tid = threadIdx.x;
    if (tid == 0) carry_s = 0;
    __syncthreads();
    for (int c0 = 0; c0 < 4 * NBUCK; c0 += 1024) {
        int i = c0 + tid;
        int val = (i < 4 * NBUCK) ? cnt[i] : 0;
        buf[tid] = val;
        __syncthreads();
        for (int off = 1; off < 1024; off <<= 1) {
            int t = (tid >= off) ? buf[tid - off] : 0;
            __syncthreads();
            buf[tid] += t;
            __syncthreads();
        }
        int carry = carry_s;
        if (i < 4 * NBUCK) base[i] = carry + buf[tid] - val;
        __syncthreads();
        if (tid == 1023) carry_s = carry + buf[1023];
        __syncthreads();
    }
    if (tid == 0) *total_out = carry_s;
}

// ---------------- pass D — finalize bucket: rowptr + compact ushort col ----------------
__global__ __launch_bounds__(256) void bucket_finalize(
    const unsigned int* __restrict__ pairbuf, const int* __restrict__ cursor,
    const int* __restrict__ base_arr, int* __restrict__ rowptr,
    unsigned short* __restrict__ col16) {
    int b = blockIdx.x;                  // 0..4*NBUCK-1
    int rel = b / NBUCK;
    int bb = b - rel * NBUCK;
    int cnt = cursor[b];
    if (cnt > BCAP) cnt = BCAP;
    int base = base_arr[b];
    const unsigned int* items = pairbuf + (size_t)b * BCAP;
    __shared__ int lcnt[128];
    __shared__ int lpfx[128];
    __shared__ int lcur[128];
    int tid = threadIdx.x;
    if (tid < 128) { lcnt[tid] = 0; lcur[tid] = 0; }
    __syncthreads();
    for (int i = tid; i < cnt; i += 256) atomicAdd(&lcnt[(items[i] >> 16) & 127], 1);
    __syncthreads();
    if (tid < 128) lpfx[tid] = lcnt[tid];
    __syncthreads();
    for (int off = 1; off < 128; off <<= 1) {
        int t = (tid < 128 && tid >= off) ? lpfx[tid - off] : 0;
        __syncthreads();
        if (tid < 128) lpfx[tid] += t;
        __syncthreads();
    }
    int node0 = bb * 128;
    if (tid < 128 && node0 + tid < ND)
        rowptr[rel * ND + node0 + tid] = base + lpfx[tid] - lcnt[tid];
    __syncthreads();
    for (int i = tid; i < cnt; i += 256) {
        unsigned int vv = items[i];
        int nl = (vv >> 16) & 127;
        int idx = atomicAdd(&lcur[nl], 1);
        col16[base + (lpfx[nl] - lcnt[nl]) + idx] = (unsigned short)(vv & 0xffffu);
    }
}

// ---------------- fused 4-relation segment gather-sum, channel-split 2-pass ----------------
// 8 nodes per wave (sub = 8 lanes x 16 B), depth-8 edge pipeline, NT output stores
// (agg is consumed once, sequentially, by the GEMM -> safe to bypass cache).
struct GatherArgs {
    const unsigned short* h[4];
    unsigned short* out[4];
    const int* rowptr;          // concatenated, rel r node v -> rowptr[r*ND+v]
    const unsigned short* col;  // concatenated u16 src slots
};

static __device__ __forceinline__ void addq(uint4 q, float2* acc) {
    acc[0] += make_float2(__uint_as_float(q.x << 16), __uint_as_float(q.x & 0xffff0000u));
    acc[1] += make_float2(__uint_as_float(q.y << 16), __uint_as_float(q.y & 0xffff0000u));
    acc[2] += make_float2(__uint_as_float(q.z << 16), __uint_as_float(q.z & 0xffff0000u));
    acc[3] += make_float2(__uint_as_float(q.w << 16), __uint_as_float(q.w & 0xffff0000u));
}

__global__ __launch_bounds__(256) void seg_gather8(GatherArgs ga, int pass) {
    int bid = blockIdx.x;                     // grid = GGRID8
    int rel = (bid & 7) >> 1;                 // XCD pair per relation
    int rb = ((bid >> 3) << 1) | (bid & 1);   // within-rel block index, [0,1564)
    int wib = threadIdx.x >> 6;
    int lane = threadIdx.x & 63;
    int sub = lane >> 3;                      // node slot within wave (8 nodes)
    int cl = (lane & 7) + pass * 8;           // 16 B slot within the half-row
    int v = rb * 32 + wib * 8 + sub;          // node id (may exceed ND)

    const uint4* h32 = reinterpret_cast<const uint4*>(ga.h[rel]);
    const int* rp = ga.rowptr + rel * ND;
    int s0 = 0, s1 = 0;
    if (v < ND) { s0 = rp[v]; s1 = rp[v + 1]; }
    const unsigned short* col = ga.col;

    float2 acc[4];
    acc[0] = acc[1] = acc[2] = acc[3] = make_float2(0.f, 0.f);

    int e = s0;
    for (; e + 8 <= s1; e += 8) {             // 8 independent edges in flight
        int si[8];
        #pragma unroll
        for (int j = 0; j < 8; ++j) si[j] = col[e + j];
        uint4 q[8];
        #pragma unroll
        for (int j = 0; j < 8; ++j) q[j] = h32[si[j] * 16 + cl];
        #pragma unroll
        for (int j = 0; j < 8; ++j) addq(q[j], acc);
    }
    if (e + 4 <= s1) {
        int s0_ = col[e], s1_ = col[e + 1], s2_ = col[e + 2], s3_ = col[e + 3];
        uint4 q0 = h32[s0_ * 16 + cl];
        uint4 q1 = h32[s1_ * 16 + cl];
        uint4 q2 = h32[s2_ * 16 + cl];
        uint4 q3 = h32[s3_ * 16 + cl];
        addq(q0, acc); addq(q1, acc); addq(q2, acc); addq(q3, acc);
        e += 4;
    }
    if (e + 2 <= s1) {
        int s0_ = col[e], s1_ = col[e + 1];
        uint4 q0 = h32[s0_ * 16 + cl];
        uint4 q1 = h32[s1_ * 16 + cl];
        addq(q0, acc); addq(q1, acc);
        e += 2;
    }
    if (e < s1) {
        uint4 q0 = h32[col[e] * 16 + cl];
        addq(q0, acc);
    }

    if (v < ND) {
        u32x4 o;
        o.x = cvt_pk_bf16(acc[0].x, acc[0].y);
        o.y = cvt_pk_bf16(acc[1].x, acc[1].y);
        o.z = cvt_pk_bf16(acc[2].x, acc[2].y);
        o.w = cvt_pk_bf16(acc[3].x, acc[3].y);
        __builtin_nontemporal_store(
            o, reinterpret_cast<u32x4*>(ga.out[rel]) + ((size_t)v * 16 + cl));
    }
}

// ---------------- fused MFMA GEMM, drug+protein halves ----------------
// 512 threads = 8 waves, 16 rows/wave, single 32 KB LDS W buffer, A prefetch 1 mat ahead.
// Layer-1 outb: REGULAR stores (od1 must stay cache-resident for layer-2's random
// gather -- r18 lesson: NT here costs 20 us downstream). Layer-2 outf: NT stores
// (final output, no consumer).
struct GemmArgs {
    const unsigned short* A[6];
    const unsigned short* W[6];
    const float* R[2];
    float* outf[2];
    unsigned short* outb[2];
    int M;
};

#define STAGE_W(Wm)                                                             \
    _Pragma("unroll")                                                           \
    for (int j = 0; j < 4; ++j)                                                 \
        gl_lds16((Wm) + (j * 512 + tid) * 8, &Wlds[(j * 512 + tid) * 8]);

#define COMPUTE_MAT()                                                           \
    _Pragma("unroll")                                                           \
    for (int s = 0; s < 4; ++s) {                                               \
        _Pragma("unroll")                                                       \
        for (int nt = 0; nt < 8; ++nt) {                                        \
            bf16x8 bb = *reinterpret_cast<const bf16x8*>(                       \
                &Wlds[((nt * 4 + s) * 64 + l) * 8]);                            \
            acc[nt] = __builtin_amdgcn_mfma_f32_16x16x32_bf16(                  \
                acur[s], bb, acc[nt], 0, 0, 0);                                 \
        }                                                                       \
    }

__global__ __launch_bounds__(512, 6) void mfma_gemm2(GemmArgs ga) {
    __shared__ unsigned short Wlds[16384];   // 32 KB: one packed W matrix

    int bid = blockIdx.x;
    int half = (bid >= GB) ? 1 : 0;
    int b = bid - half * GB;
    const float* R = ga.R[half];
    float* outf = ga.outf[half];
    unsigned short* outb = ga.outb[half];
    int M = ga.M;

    int tid = threadIdx.x;
    int w = tid >> 6;            // wave 0..7
    int l = tid & 63;
    int lrow = l & 15;
    int lk = l >> 4;
    int m0 = b * 128 + w * 16;   // 16 rows per wave

    size_t rowoff = (size_t)(m0 + lrow) * CH + lk * 8;

    const unsigned short* A0 = ga.A[half * 3 + 0];
    const unsigned short* A1 = ga.A[half * 3 + 1];
    const unsigned short* A2 = ga.A[half * 3 + 2];

    bf16x8 acur[4], anx[4];
    #pragma unroll
    for (int s = 0; s < 4; ++s)
        acur[s] = *reinterpret_cast<const bf16x8*>(A0 + rowoff + s * 32);
    STAGE_W(ga.W[half * 3 + 0]);

    f32x4 acc[8];
    #pragma unroll
    for (int nt = 0; nt < 8; ++nt) acc[nt] = (f32x4){0.f, 0.f, 0.f, 0.f};

    __syncthreads();                               // W0 staged, acur ready
    #pragma unroll
    for (int s = 0; s < 4; ++s)                    // prefetch A1 (overlaps MFMA)
        anx[s] = *reinterpret_cast<const bf16x8*>(A1 + rowoff + s * 32);
    COMPUTE_MAT();
    __syncthreads();                               // LDS free
    STAGE_W(ga.W[half * 3 + 1]);
    #pragma unroll
    for (int s = 0; s < 4; ++s) acur[s] = anx[s];
    __syncthreads();                               // W1 staged
    #pragma unroll
    for (int s = 0; s < 4; ++s)                    // prefetch A2
        anx[s] = *reinterpret_cast<const bf16x8*>(A2 + rowoff + s * 32);
    COMPUTE_MAT();
    __syncthreads();                               // LDS free
    STAGE_W(ga.W[half * 3 + 2]);
    #pragma unroll
    for (int s = 0; s < 4; ++s) acur[s] = anx[s];
    __syncthreads();                               // W2 staged
    COMPUTE_MAT();

    if (outf) {
        // layer 2: LDS transpose (2 chunks of 64 rows) -> coalesced residual + NT store
        float* lf = reinterpret_cast<float*>(Wlds);    // 32 KB = 64 rows x 128 fp32
        #pragma unroll
        for (int c = 0; c < 2; ++c) {
            __syncthreads();                           // LDS free for this chunk
            if ((w >> 2) == c) {
                int lr = (w & 3) * 16 + lk * 4;
                #pragma unroll
                for (int r = 0; r < 4; ++r)
                    #pragma unroll
                    for (int nt = 0; nt < 8; ++nt)
                        lf[(lr + r) * 128 + nt * 16 + lrow] = acc[nt][r];
            }
            __syncthreads();
            int rowbase = b * 128 + c * 64;
            #pragma unroll
            for (int k = 0; k < 4; ++k) {
                int f4 = k * 512 + tid;                // 64 rows x 32 float4
                int lr = f4 >> 5;
                int fc = f4 & 31;
                int row = rowbase + lr;
                if (row < M) {
                    f32x4 v = reinterpret_cast<f32x4*>(lf)[f4];
                    const float* rp = R + (size_t)row * CH + fc * 4;
                    f32x4 rv = *reinterpret_cast<const f32x4*>(rp);
                    v.x = fmaxf(v.x + rv.x, 0.f);
                    v.y = fmaxf(v.y + rv.y, 0.f);
                    v.z = fmaxf(v.z + rv.z, 0.f);
                    v.w = fmaxf(v.w + rv.w, 0.f);
                    __builtin_nontemporal_store(
                        v, reinterpret_cast<f32x4*>(outf + (size_t)row * CH + fc * 4));
                }
            }
        }
    } else {
        // layer 1: K-permuted bf16, one REGULAR uint4 store per r (keep od1 cached)
        #pragma unroll
        for (int r = 0; r < 4; ++r) {
            int row = m0 + lk * 4 + r;
            if (row < M) {
                uint4 o;
                o.x = cvt_pk_bf16(fmaxf(acc[0][r], 0.f), fmaxf(acc[1][r], 0.f));
                o.y = cvt_pk_bf16(fmaxf(acc[2][r], 0.f), fmaxf(acc[3][r], 0.f));
                o.z = cvt_pk_bf16(fmaxf(acc[4][r], 0.f), fmaxf(acc[5][r], 0.f));
                o.w = cvt_pk_bf16(fmaxf(acc[6][r], 0.f), fmaxf(acc[7][r], 0.f));
                *reinterpret_cast<uint4*>(outb + (size_t)row * CH + lrow * 8) = o;
            }
        }
    }
}

// ---------------- launch ----------------

extern "C" void kernel_launch(void* const* d_in, const int* in_sizes, int n_in,
                              void* d_out, int out_size, void* d_ws, size_t ws_size,
                              hipStream_t stream) {
    const float* hd = (const float*)d_in[0];
    const float* hp = (const float*)d_in[1];

    float* outd = (float*)d_out;
    float* outp = outd + (size_t)ND * CH;

    char* ws = (char*)d_ws;
    size_t off = 0;
    auto alloc = [&](size_t bytes) -> char* {
        char* p = ws + off;
        off += (bytes + 255) & ~(size_t)255;
        return p;
    };
    int* rowptr = (int*)alloc((size_t)(NREL4 + 1) * 4);
    int* cursor = (int*)alloc((size_t)4 * NBUCK * 4);
    int* bbase = (int*)alloc((size_t)4 * NBUCK * 4);
    unsigned int* pairbuf = (unsigned int*)alloc((size_t)4 * NBUCK * BCAP * 4);
    unsigned short* col16 = (unsigned short*)alloc((size_t)4 * NEDGE * 2);
    unsigned short* hdb = (unsigned short*)alloc((size_t)MP * CH * 2);
    unsigned short* hpb = (unsigned short*)alloc((size_t)MP * CH * 2);
    unsigned short* od1d = (unsigned short*)alloc((size_t)MP * CH * 2);
    unsigned short* od1p = (unsigned short*)alloc((size_t)MP * CH * 2);
    unsigned short* agg[4];
    for (int r = 0; r < 4; ++r) agg[r] = (unsigned short*)alloc((size_t)MP * CH * 2);
    unsigned short* wfrag = (unsigned short*)alloc((size_t)12 * 16384 * 2);
    if (ws_size < off) return;  // workspace too small -> fail loudly

    const unsigned short* wf[12];
    for (int i = 0; i < 12; ++i) wf[i] = wfrag + (size_t)i * 16384;

    // ---- fused prep: scatter || f2b2 || pack_w  (rel order {dd, dp, pd, pp}) ----
    hipMemsetAsync(cursor, 0, (size_t)4 * NBUCK * 4, stream);
    PrepArgs pa;
    pa.s[0] = (const int*)d_in[2]; pa.s[1] = (const int*)d_in[3];
    pa.s[2] = (const int*)d_in[4]; pa.s[3] = (const int*)d_in[5];
    for (int r = 0; r < 4; ++r) pa.d[r] = pa.s[r] + NEDGE;
    pa.cursor = cursor; pa.pairbuf = pairbuf;
    pa.hd = hd; pa.hp = hp; pa.hdb = hdb; pa.hpb = hpb;
    for (int i = 0; i < 12; ++i) pa.w[i] = (const float*)d_in[6 + i];
    pa.wf = wfrag;
    prep_kernel<<<PREP_BLOCKS, 256, 0, stream>>>(pa);
    scan_buckets<<<1, 1024, 0, stream>>>(cursor, bbase, rowptr + NREL4);
    bucket_finalize<<<4 * NBUCK, 256, 0, stream>>>(pairbuf, cursor, bbase, rowptr, col16);

    // ---- layer 1 ----
    GatherArgs g1;
    g1.h[0] = hdb; g1.out[0] = agg[0];   // dd -> agg_dd
    g1.h[1] = hdb; g1.out[1] = agg[3];   // dp -> agg_dp
    g1.h[2] = hpb; g1.out[2] = agg[1];   // pd -> agg_pd
    g1.h[3] = hpb; g1.out[3] = agg[2];   // pp -> agg_pp
    g1.rowptr = rowptr; g1.col = col16;
    seg_gather8<<<GGRID8, 256, 0, stream>>>(g1, 0);
    seg_gather8<<<GGRID8, 256, 0, stream>>>(g1, 1);

    GemmArgs m1;
    m1.A[0] = hdb;  m1.A[1] = agg[0]; m1.A[2] = agg[1];
    m1.W[0] = wf[0]; m1.W[1] = wf[2]; m1.W[2] = wf[4];   // w1_sd, w1_dd, w1_pd
    m1.A[3] = hpb;  m1.A[4] = agg[2]; m1.A[5] = agg[3];
    m1.W[3] = wf[1]; m1.W[4] = wf[5]; m1.W[5] = wf[3];   // w1_sp, w1_pp, w1_dp
    m1.R[0] = nullptr; m1.R[1] = nullptr;
    m1.outf[0] = nullptr; m1.outf[1] = nullptr;
    m1.outb[0] = od1d; m1.outb[1] = od1p;
    m1.M = ND;
    mfma_gemm2<<<2 * GB, 512, 0, stream>>>(m1);

    // ---- layer 2 (od1 & its aggs live in K-permuted space; wf[6..11] match) ----
    GatherArgs g2 = g1;
    g2.h[0] = od1d; g2.h[1] = od1d; g2.h[2] = od1p; g2.h[3] = od1p;
    seg_gather8<<<GGRID8, 256, 0, stream>>>(g2, 0);
    seg_gather8<<<GGRID8, 256, 0, stream>>>(g2, 1);

    GemmArgs m2;
    m2.A[0] = od1d; m2.A[1] = agg[0]; m2.A[2] = agg[1];
    m2.W[0] = wf[6]; m2.W[1] = wf[8]; m2.W[2] = wf[10];  // w2_sd, w2_dd, w2_pd
    m2.A[3] = od1p; m2.A[4] = agg[2]; m2.A[5] = agg[3];
    m2.W[3] = wf[7]; m2.W[4] = wf[11]; m2.W[5] = wf[9];  // w2_sp, w2_pp, w2_dp
    m2.R[0] = hd; m2.R[1] = hp;
    m2.outf[0] = outd; m2.outf[1] = outp;
    m2.outb[0] = nullptr; m2.outb[1] = nullptr;
    m2.M = ND;
    mfma_gemm2<<<2 * GB, 512, 0, stream>>>(m2);
}

// Round 20
// 247.956 us; speedup vs baseline: 1.0511x; 1.0291x over previous
//
#include <hip/hip_runtime.h>

#define ND 50000
#define NEDGE 640000
#define CH 128
#define MP 50048          // 391*128 padded rows
#define NREL4 (4 * ND)    // 200000
#define GB (MP / 128)     // 391 blocks per GEMM half
#define NBUCK 391         // buckets per relation (128 nodes each)
#define BCAP 2000         // padded bucket capacity (mean 1638, sigma 40)
#define CHUNK 4096        // edges per scatter block
#define EPT 16            // edges per thread in scatter

#define NCHUNKS ((NEDGE + CHUNK - 1) / CHUNK)   // 157
#define SCAT_BLOCKS (4 * NCHUNKS)               // 628
#define F2B_BLOCKS (2 * (ND * CH / 4) / 256)    // 12500
#define PACKW_BLOCKS ((12 * 16384) / 256)       // 768
#define PREP_BLOCKS (SCAT_BLOCKS + F2B_BLOCKS + PACKW_BLOCKS)

#define GGRID8 6256   // 8 * 782; per rel 1564 rb-slots * 32 nodes >= ND

using f32x4 = __attribute__((ext_vector_type(4))) float;
using bf16x8 = __attribute__((ext_vector_type(8))) __bf16;
using u32x4 = __attribute__((ext_vector_type(4))) unsigned int;
using u32x2 = __attribute__((ext_vector_type(2))) unsigned int;

static __device__ __forceinline__ unsigned short f2bf(float f) {
    unsigned int u = __float_as_uint(f);
    unsigned int r = (u + 0x7fffu + ((u >> 16) & 1u)) >> 16;
    return (unsigned short)r;
}

// v_cvt_pk_bf16_f32: packs RNE(lo), RNE(hi) into one u32 (gfx950; no builtin)
static __device__ __forceinline__ unsigned int cvt_pk_bf16(float lo, float hi) {
    unsigned int r;
    asm volatile("v_cvt_pk_bf16_f32 %0, %1, %2" : "=v"(r) : "v"(lo), "v"(hi));
    return r;
}

// async global->LDS, 16 B per lane; dest linear => wave-uniform-base + lane*16 holds
static __device__ __forceinline__ void gl_lds16(const unsigned short* g, unsigned short* l) {
    __builtin_amdgcn_global_load_lds(
        (const __attribute__((address_space(1))) unsigned int*)g,
        (__attribute__((address_space(3))) unsigned int*)l, 16, 0, 0);
}

// ---------------- fused prep: edge scatter  ||  fp32->bf16 convert  ||  W pack ----------------
struct PrepArgs {
    const int* s[4];            // src arrays per rel
    const int* d[4];            // dst arrays per rel
    int* cursor;                // [4*NBUCK], zeroed before launch
    unsigned int* pairbuf;
    const float* hd;
    const float* hp;
    unsigned short* hdb;
    unsigned short* hpb;
    const float* w[12];
    unsigned short* wf;
};

__global__ __launch_bounds__(256) void prep_kernel(PrepArgs pa) {
    __shared__ int lcnt[NBUCK];
    __shared__ int lbase[NBUCK];
    __shared__ int lcur[NBUCK];
    int bid = blockIdx.x;
    int tid = threadIdx.x;

    if (bid < SCAT_BLOCKS) {
        // ---- pass C: scatter edges into coarse buckets ----
        int rel = bid / NCHUNKS;
        int chunk = bid - rel * NCHUNKS;
        const int* S = pa.s[rel];
        const int* D = pa.d[rel];
        int e0 = chunk * CHUNK;
        int cnt_edges = NEDGE - e0;
        if (cnt_edges > CHUNK) cnt_edges = CHUNK;
        for (int i = tid; i < NBUCK; i += 256) { lcnt[i] = 0; lcur[i] = 0; }
        __syncthreads();
        unsigned int v[EPT];
        #pragma unroll
        for (int i = 0; i < EPT; ++i) {
            int o = i * 256 + tid;
            if (o < cnt_edges) {
                unsigned int sv = (unsigned int)S[e0 + o];
                unsigned int dv = (unsigned int)D[e0 + o];
                v[i] = sv | (dv << 16);
                atomicAdd(&lcnt[dv >> 7], 1);
            }
        }
        __syncthreads();
        for (int b = tid; b < NBUCK; b += 256) {
            int c = lcnt[b];
            if (c > 0) {
                int off = atomicAdd(&pa.cursor[rel * NBUCK + b], c);
                lbase[b] = (rel * NBUCK + b) * BCAP + off;
            }
        }
        __syncthreads();
        #pragma unroll
        for (int i = 0; i < EPT; ++i) {
            int o = i * 256 + tid;
            if (o < cnt_edges) {
                unsigned int vv = v[i];
                int b = vv >> 23;            // dst >> 7
                int idx = atomicAdd(&lcur[b], 1);
                int go = lbase[b] + idx - (rel * NBUCK + b) * BCAP;
                if (go < BCAP) pa.pairbuf[lbase[b] + idx] = vv;
            }
        }
    } else if (bid < SCAT_BLOCKS + F2B_BLOCKS) {
        // ---- fp32 -> bf16 bulk convert, both tables ----
        const int n4 = ND * CH / 4;
        int i = (bid - SCAT_BLOCKS) * 256 + tid;   // [0, 2*n4)
        const float* in = pa.hd;
        unsigned short* out = pa.hdb;
        int j = i;
        if (i >= n4) { in = pa.hp; out = pa.hpb; j = i - n4; }
        float4 v = reinterpret_cast<const float4*>(in)[j];
        uint2 o;
        o.x = cvt_pk_bf16(v.x, v.y);
        o.y = cvt_pk_bf16(v.z, v.w);
        reinterpret_cast<uint2*>(out)[j] = o;
    } else {
        // ---- W pack: fp32 [k][n] -> bf16 MFMA B-fragment order ----
        // layer-2 mats (6..11): K-permuted to match the permuted od1 storage:
        // storage position p holds original channel c(p) = (p>>3) | ((p&7)<<4)
        int idx = (bid - SCAT_BLOCKS - F2B_BLOCKS) * 256 + tid;   // [0, 12*16384)
        int mat = idx >> 14;
        const float* W = pa.w[mat];
        int r = idx & 16383;
        int j = r & 7;
        int l = (r >> 3) & 63;
        int s = (r >> 9) & 3;
        int nt = (r >> 11) & 7;
        int k = s * 32 + ((l >> 4) << 3) + j;
        if (mat >= 6) k = (k >> 3) | ((k & 7) << 4);
        int n = nt * 16 + (l & 15);
        pa.wf[idx] = f2bf(W[k * CH + n]);
    }
}

// ---------------- pass B' — scan 1564 bucket counts -> global CSR bases ----------------
__global__ __launch_bounds__(1024) void scan_buckets(const int* __restrict__ cnt,
                                                     int* __restrict__ base,
                                                     int* __restrict__ total_out) {
    __shared__ int buf[1024];
    __shared__ int carry_s;
    int tid = threadIdx.x;
    if (tid == 0) carry_s = 0;
    __syncthreads();
    for (int c0 = 0; c0 < 4 * NBUCK; c0 += 1024) {
        int i = c0 + tid;
        int val = (i < 4 * NBUCK) ? cnt[i] : 0;
        buf[tid] = val;
        __syncthreads();
        for (int off = 1; off < 1024; off <<= 1) {
            int t = (tid >= off) ? buf[tid - off] : 0;
            __syncthreads();
            buf[tid] += t;
            __syncthreads();
        }
        int carry = carry_s;
        if (i < 4 * NBUCK) base[i] = carry + buf[tid] - val;
        __syncthreads();
        if (tid == 1023) carry_s = carry + buf[1023];
        __syncthreads();
    }
    if (tid == 0) *total_out = carry_s;
}

// ---------------- pass D — finalize bucket: rowptr + compact ushort col ----------------
__global__ __launch_bounds__(256) void bucket_finalize(
    const unsigned int* __restrict__ pairbuf, const int* __restrict__ cursor,
    const int* __restrict__ base_arr, int* __restrict__ rowptr,
    unsigned short* __restrict__ col16) {
    int b = blockIdx.x;                  // 0..4*NBUCK-1
    int rel = b / NBUCK;
    int bb = b - rel * NBUCK;
    int cnt = cursor[b];
    if (cnt > BCAP) cnt = BCAP;
    int base = base_arr[b];
    const unsigned int* items = pairbuf + (size_t)b * BCAP;
    __shared__ int lcnt[128];
    __shared__ int lpfx[128];
    __shared__ int lcur[128];
    int tid = threadIdx.x;
    if (tid < 128) { lcnt[tid] = 0; lcur[tid] = 0; }
    __syncthreads();
    for (int i = tid; i < cnt; i += 256) atomicAdd(&lcnt[(items[i] >> 16) & 127], 1);
    __syncthreads();
    if (tid < 128) lpfx[tid] = lcnt[tid];
    __syncthreads();
    for (int off = 1; off < 128; off <<= 1) {
        int t = (tid < 128 && tid >= off) ? lpfx[tid - off] : 0;
        __syncthreads();
        if (tid < 128) lpfx[tid] += t;
        __syncthreads();
    }
    int node0 = bb * 128;
    if (tid < 128 && node0 + tid < ND)
        rowptr[rel * ND + node0 + tid] = base + lpfx[tid] - lcnt[tid];
    __syncthreads();
    for (int i = tid; i < cnt; i += 256) {
        unsigned int vv = items[i];
        int nl = (vv >> 16) & 127;
        int idx = atomicAdd(&lcur[nl], 1);
        col16[base + (lpfx[nl] - lcnt[nl]) + idx] = (unsigned short)(vv & 0xffffu);
    }
}

// ---------------- fused 4-relation segment gather-sum, channel-split 2-pass ----------------
// 8 nodes per wave (sub = 8 lanes x 16 B), depth-8 edge pipeline, NT output stores.
struct GatherArgs {
    const unsigned short* h[4];
    unsigned short* out[4];
    const int* rowptr;          // concatenated, rel r node v -> rowptr[r*ND+v]
    const unsigned short* col;  // concatenated u16 src slots
};

static __device__ __forceinline__ void addq(uint4 q, float2* acc) {
    acc[0] += make_float2(__uint_as_float(q.x << 16), __uint_as_float(q.x & 0xffff0000u));
    acc[1] += make_float2(__uint_as_float(q.y << 16), __uint_as_float(q.y & 0xffff0000u));
    acc[2] += make_float2(__uint_as_float(q.z << 16), __uint_as_float(q.z & 0xffff0000u));
    acc[3] += make_float2(__uint_as_float(q.w << 16), __uint_as_float(q.w & 0xffff0000u));
}

__global__ __launch_bounds__(256) void seg_gather8(GatherArgs ga, int pass) {
    int bid = blockIdx.x;                     // grid = GGRID8
    int rel = (bid & 7) >> 1;                 // XCD pair per relation
    int rb = ((bid >> 3) << 1) | (bid & 1);   // within-rel block index, [0,1564)
    int wib = threadIdx.x >> 6;
    int lane = threadIdx.x & 63;
    int sub = lane >> 3;                      // node slot within wave (8 nodes)
    int cl = (lane & 7) + pass * 8;           // 16 B slot within the half-row
    int v = rb * 32 + wib * 8 + sub;          // node id (may exceed ND)

    const uint4* h32 = reinterpret_cast<const uint4*>(ga.h[rel]);
    const int* rp = ga.rowptr + rel * ND;
    int s0 = 0, s1 = 0;
    if (v < ND) { s0 = rp[v]; s1 = rp[v + 1]; }
    const unsigned short* col = ga.col;

    float2 acc[4];
    acc[0] = acc[1] = acc[2] = acc[3] = make_float2(0.f, 0.f);

    int e = s0;
    for (; e + 8 <= s1; e += 8) {             // 8 independent edges in flight
        int si[8];
        #pragma unroll
        for (int j = 0; j < 8; ++j) si[j] = col[e + j];
        uint4 q[8];
        #pragma unroll
        for (int j = 0; j < 8; ++j) q[j] = h32[si[j] * 16 + cl];
        #pragma unroll
        for (int j = 0; j < 8; ++j) addq(q[j], acc);
    }
    if (e + 4 <= s1) {
        int s0_ = col[e], s1_ = col[e + 1], s2_ = col[e + 2], s3_ = col[e + 3];
        uint4 q0 = h32[s0_ * 16 + cl];
        uint4 q1 = h32[s1_ * 16 + cl];
        uint4 q2 = h32[s2_ * 16 + cl];
        uint4 q3 = h32[s3_ * 16 + cl];
        addq(q0, acc); addq(q1, acc); addq(q2, acc); addq(q3, acc);
        e += 4;
    }
    if (e + 2 <= s1) {
        int s0_ = col[e], s1_ = col[e + 1];
        uint4 q0 = h32[s0_ * 16 + cl];
        uint4 q1 = h32[s1_ * 16 + cl];
        addq(q0, acc); addq(q1, acc);
        e += 2;
    }
    if (e < s1) {
        uint4 q0 = h32[col[e] * 16 + cl];
        addq(q0, acc);
    }

    if (v < ND) {
        u32x4 o;
        o.x = cvt_pk_bf16(acc[0].x, acc[0].y);
        o.y = cvt_pk_bf16(acc[1].x, acc[1].y);
        o.z = cvt_pk_bf16(acc[2].x, acc[2].y);
        o.w = cvt_pk_bf16(acc[3].x, acc[3].y);
        __builtin_nontemporal_store(
            o, reinterpret_cast<u32x4*>(ga.out[rel]) + ((size_t)v * 16 + cl));
    }
}

// ---------------- fused MFMA GEMM, drug+protein halves ----------------
// 512 threads = 8 waves, 16 rows/wave, single 32 KB LDS W buffer, A prefetch 1 mat ahead.
// Layer-1 out: K-permuted bf16 uint4 stores. Layer-2: LDS-transpose coalesced epilogue.
struct GemmArgs {
    const unsigned short* A[6];
    const unsigned short* W[6];
    const float* R[2];
    float* outf[2];
    unsigned short* outb[2];
    int M;
};

#define STAGE_W(Wm)                                                             \
    _Pragma("unroll")                                                           \
    for (int j = 0; j < 4; ++j)                                                 \
        gl_lds16((Wm) + (j * 512 + tid) * 8, &Wlds[(j * 512 + tid) * 8]);

#define COMPUTE_MAT()                                                           \
    _Pragma("unroll")                                                           \
    for (int s = 0; s < 4; ++s) {                                               \
        _Pragma("unroll")                                                       \
        for (int nt = 0; nt < 8; ++nt) {                                        \
            bf16x8 bb = *reinterpret_cast<const bf16x8*>(                       \
                &Wlds[((nt * 4 + s) * 64 + l) * 8]);                            \
            acc[nt] = __builtin_amdgcn_mfma_f32_16x16x32_bf16(                  \
                acur[s], bb, acc[nt], 0, 0, 0);                                 \
        }                                                                       \
    }

__global__ __launch_bounds__(512, 6) void mfma_gemm2(GemmArgs ga) {
    __shared__ unsigned short Wlds[16384];   // 32 KB: one packed W matrix

    int bid = blockIdx.x;
    int half = (bid >= GB) ? 1 : 0;
    int b = bid - half * GB;
    const float* R = ga.R[half];
    float* outf = ga.outf[half];
    unsigned short* outb = ga.outb[half];
    int M = ga.M;

    int tid = threadIdx.x;
    int w = tid >> 6;            // wave 0..7
    int l = tid & 63;
    int lrow = l & 15;
    int lk = l >> 4;
    int m0 = b * 128 + w * 16;   // 16 rows per wave

    size_t rowoff = (size_t)(m0 + lrow) * CH + lk * 8;

    const unsigned short* A0 = ga.A[half * 3 + 0];
    const unsigned short* A1 = ga.A[half * 3 + 1];
    const unsigned short* A2 = ga.A[half * 3 + 2];

    bf16x8 acur[4], anx[4];
    #pragma unroll
    for (int s = 0; s < 4; ++s)
        acur[s] = *reinterpret_cast<const bf16x8*>(A0 + rowoff + s * 32);
    STAGE_W(ga.W[half * 3 + 0]);

    f32x4 acc[8];
    #pragma unroll
    for (int nt = 0; nt < 8; ++nt) acc[nt] = (f32x4){0.f, 0.f, 0.f, 0.f};

    __syncthreads();                               // W0 staged, acur ready
    #pragma unroll
    for (int s = 0; s < 4; ++s)                    // prefetch A1 (overlaps MFMA)
        anx[s] = *reinterpret_cast<const bf16x8*>(A1 + rowoff + s * 32);
    COMPUTE_MAT();
    __syncthreads();                               // LDS free
    STAGE_W(ga.W[half * 3 + 1]);
    #pragma unroll
    for (int s = 0; s < 4; ++s) acur[s] = anx[s];
    __syncthreads();                               // W1 staged
    #pragma unroll
    for (int s = 0; s < 4; ++s)                    // prefetch A2
        anx[s] = *reinterpret_cast<const bf16x8*>(A2 + rowoff + s * 32);
    COMPUTE_MAT();
    __syncthreads();                               // LDS free
    STAGE_W(ga.W[half * 3 + 2]);
    #pragma unroll
    for (int s = 0; s < 4; ++s) acur[s] = anx[s];
    __syncthreads();                               // W2 staged
    COMPUTE_MAT();

    if (outf) {
        // layer 2: LDS transpose (2 chunks of 64 rows) -> coalesced residual+store
        float* lf = reinterpret_cast<float*>(Wlds);    // 32 KB = 64 rows x 128 fp32
        #pragma unroll
        for (int c = 0; c < 2; ++c) {
            __syncthreads();                           // LDS free for this chunk
            if ((w >> 2) == c) {
                int lr = (w & 3) * 16 + lk * 4;
                #pragma unroll
                for (int r = 0; r < 4; ++r)
                    #pragma unroll
                    for (int nt = 0; nt < 8; ++nt)
                        lf[(lr + r) * 128 + nt * 16 + lrow] = acc[nt][r];
            }
            __syncthreads();
            int rowbase = b * 128 + c * 64;
            #pragma unroll
            for (int k = 0; k < 4; ++k) {
                int f4 = k * 512 + tid;                // 64 rows x 32 float4
                int lr = f4 >> 5;
                int fc = f4 & 31;
                int row = rowbase + lr;
                if (row < M) {
                    float4 v = reinterpret_cast<float4*>(lf)[f4];
                    float4 rv = *reinterpret_cast<const float4*>(R + (size_t)row * CH + fc * 4);
                    v.x = fmaxf(v.x + rv.x, 0.f);
                    v.y = fmaxf(v.y + rv.y, 0.f);
                    v.z = fmaxf(v.z + rv.z, 0.f);
                    v.w = fmaxf(v.w + rv.w, 0.f);
                    *reinterpret_cast<float4*>(outf + (size_t)row * CH + fc * 4) = v;
                }
            }
        }
    } else {
        // layer 1: K-permuted bf16, one uint4 store per r
        #pragma unroll
        for (int r = 0; r < 4; ++r) {
            int row = m0 + lk * 4 + r;
            if (row < M) {
                uint4 o;
                o.x = cvt_pk_bf16(fmaxf(acc[0][r], 0.f), fmaxf(acc[1][r], 0.f));
                o.y = cvt_pk_bf16(fmaxf(acc[2][r], 0.f), fmaxf(acc[3][r], 0.f));
                o.z = cvt_pk_bf16(fmaxf(acc[4][r], 0.f), fmaxf(acc[5][r], 0.f));
                o.w = cvt_pk_bf16(fmaxf(acc[6][r], 0.f), fmaxf(acc[7][r], 0.f));
                *reinterpret_cast<uint4*>(outb + (size_t)row * CH + lrow * 8) = o;
            }
        }
    }
}

// ---------------- launch ----------------

extern "C" void kernel_launch(void* const* d_in, const int* in_sizes, int n_in,
                              void* d_out, int out_size, void* d_ws, size_t ws_size,
                              hipStream_t stream) {
    const float* hd = (const float*)d_in[0];
    const float* hp = (const float*)d_in[1];

    float* outd = (float*)d_out;
    float* outp = outd + (size_t)ND * CH;

    char* ws = (char*)d_ws;
    size_t off = 0;
    auto alloc = [&](size_t bytes) -> char* {
        char* p = ws + off;
        off += (bytes + 255) & ~(size_t)255;
        return p;
    };
    int* rowptr = (int*)alloc((size_t)(NREL4 + 1) * 4);
    int* cursor = (int*)alloc((size_t)4 * NBUCK * 4);
    int* bbase = (int*)alloc((size_t)4 * NBUCK * 4);
    unsigned int* pairbuf = (unsigned int*)alloc((size_t)4 * NBUCK * BCAP * 4);
    unsigned short* col16 = (unsigned short*)alloc((size_t)4 * NEDGE * 2);
    unsigned short* hdb = (unsigned short*)alloc((size_t)MP * CH * 2);
    unsigned short* hpb = (unsigned short*)alloc((size_t)MP * CH * 2);
    unsigned short* od1d = (unsigned short*)alloc((size_t)MP * CH * 2);
    unsigned short* od1p = (unsigned short*)alloc((size_t)MP * CH * 2);
    unsigned short* agg[4];
    for (int r = 0; r < 4; ++r) agg[r] = (unsigned short*)alloc((size_t)MP * CH * 2);
    unsigned short* wfrag = (unsigned short*)alloc((size_t)12 * 16384 * 2);
    if (ws_size < off) return;  // workspace too small -> fail loudly

    const unsigned short* wf[12];
    for (int i = 0; i < 12; ++i) wf[i] = wfrag + (size_t)i * 16384;

    // ---- fused prep: scatter || f2b2 || pack_w  (rel order {dd, dp, pd, pp}) ----
    hipMemsetAsync(cursor, 0, (size_t)4 * NBUCK * 4, stream);
    PrepArgs pa;
    pa.s[0] = (const int*)d_in[2]; pa.s[1] = (const int*)d_in[3];
    pa.s[2] = (const int*)d_in[4]; pa.s[3] = (const int*)d_in[5];
    for (int r = 0; r < 4; ++r) pa.d[r] = pa.s[r] + NEDGE;
    pa.cursor = cursor; pa.pairbuf = pairbuf;
    pa.hd = hd; pa.hp = hp; pa.hdb = hdb; pa.hpb = hpb;
    for (int i = 0; i < 12; ++i) pa.w[i] = (const float*)d_in[6 + i];
    pa.wf = wfrag;
    prep_kernel<<<PREP_BLOCKS, 256, 0, stream>>>(pa);
    scan_buckets<<<1, 1024, 0, stream>>>(cursor, bbase, rowptr + NREL4);
    bucket_finalize<<<4 * NBUCK, 256, 0, stream>>>(pairbuf, cursor, bbase, rowptr, col16);

    // ---- layer 1 ----
    GatherArgs g1;
    g1.h[0] = hdb; g1.out[0] = agg[0];   // dd -> agg_dd
    g1.h[1] = hdb; g1.out[1] = agg[3];   // dp -> agg_dp
    g1.h[2] = hpb; g1.out[2] = agg[1];   // pd -> agg_pd
    g1.h[3] = hpb; g1.out[3] = agg[2];   // pp -> agg_pp
    g1.rowptr = rowptr; g1.col = col16;
    seg_gather8<<<GGRID8, 256, 0, stream>>>(g1, 0);
    seg_gather8<<<GGRID8, 256, 0, stream>>>(g1, 1);

    GemmArgs m1;
    m1.A[0] = hdb;  m1.A[1] = agg[0]; m1.A[2] = agg[1];
    m1.W[0] = wf[0]; m1.W[1] = wf[2]; m1.W[2] = wf[4];   // w1_sd, w1_dd, w1_pd
    m1.A[3] = hpb;  m1.A[4] = agg[2]; m1.A[5] = agg[3];
    m1.W[3] = wf[1]; m1.W[4] = wf[5]; m1.W[5] = wf[3];   // w1_sp, w1_pp, w1_dp
    m1.R[0] = nullptr; m1.R[1] = nullptr;
    m1.outf[0] = nullptr; m1.outf[1] = nullptr;
    m1.outb[0] = od1d; m1.outb[1] = od1p;
    m1.M = ND;
    mfma_gemm2<<<2 * GB, 512, 0, stream>>>(m1);

    // ---- layer 2 (od1 & its aggs live in K-permuted space; wf[6..11] match) ----
    GatherArgs g2 = g1;
    g2.h[0] = od1d; g2.h[1] = od1d; g2.h[2] = od1p; g2.h[3] = od1p;
    seg_gather8<<<GGRID8, 256, 0, stream>>>(g2, 0);
    seg_gather8<<<GGRID8, 256, 0, stream>>>(g2, 1);

    GemmArgs m2;
    m2.A[0] = od1d; m2.A[1] = agg[0]; m2.A[2] = agg[1];
    m2.W[0] = wf[6]; m2.W[1] = wf[8]; m2.W[2] = wf[10];  // w2_sd, w2_dd, w2_pd
    m2.A[3] = od1p; m2.A[4] = agg[2]; m2.A[5] = agg[3];
    m2.W[3] = wf[7]; m2.W[4] = wf[11]; m2.W[5] = wf[9];  // w2_sp, w2_pp, w2_dp
    m2.R[0] = hd; m2.R[1] = hp;
    m2.outf[0] = outd; m2.outf[1] = outp;
    m2.outb[0] = nullptr; m2.outb[1] = nullptr;
    m2.M = ND;
    mfma_gemm2<<<2 * GB, 512, 0, stream>>>(m2);
}